// Round 7
// baseline (160.085 us; speedup 1.0000x reference)
//
#include <hip/hip_runtime.h>
#include <math.h>

#ifndef M_PI
#define M_PI 3.14159265358979323846
#endif

namespace {
constexpr int B_ = 4;
constexpr int L_ = 2048;
constexpr int D_ = 64;
constexpr int H_ = 4;
constexpr int RB = 16;          // rows per block
constexpr int KT = 64;          // K-tile
constexpr int NTILE = L_ / KT;  // 32
constexpr int CAPC = 256;       // per-wave candidate capacity
constexpr int OUTW = D_ + H_ * D_;  // 320
constexpr int APS = 2064;       // A plane stride bytes (64*16*2 + 16 pad)
}

typedef __attribute__((ext_vector_type(8))) short bf16x8;
typedef __attribute__((ext_vector_type(4))) float f32x4;

__device__ __forceinline__ unsigned bf16_rne(float x) {
    unsigned u = __float_as_uint(x);
    return (u + 0x7fffu + ((u >> 16) & 1u)) >> 16;
}

// wait lgkmcnt(0) only (vmcnt=63, expcnt=7): gfx9 imm = (vm_hi<<14)|(lgkm<<8)|(exp<<4)|vm_lo
#define LDS_FENCE() __builtin_amdgcn_s_waitcnt(0xC07F)

__global__ __launch_bounds__(512, 8) void posatt_kernel(
    const float* __restrict__ mesh,     // (B,L,2)
    const float* __restrict__ inputs,   // (B,L,D)
    const float* __restrict__ lmda,     // (H)
    float* __restrict__ out)            // (B,L,320)
{
    __shared__ __align__(16) float2 s_mesh[L_];       // 16 KB
    // time-shared region: phase1 hist(8K)+cand(8K) | phase2 A(8256)+B(8192) | epilogue C(16K)
    __shared__ __align__(16) char s_u1[16448];
    __shared__ float s_scale[H_];
    __shared__ float s_th[RB][H_];
    __shared__ float s_d409[RB], s_d410[RB];
    __shared__ float s_wsum[RB][H_];
    __shared__ unsigned s_ccw[8];

    const int t = threadIdx.x;
    const int l = t & 63;
    const int w = t >> 6;               // 8 waves
    const int blk = blockIdx.x;         // 512
    const int b = blk >> 7;
    const int n0 = (blk & 127) * RB;

    // per-head scale (exact, verified R2 path)
    if (t < H_) {
        const double lam = (double)lmda[t];
        const float C = (float)(0.25 * M_PI * (1.0 - 1e-07));
        const float s1 = (float)sin(lam);
        const float arg = __fmul_rn(C, __fadd_rn(1.0f, s1));
        s_scale[t] = (float)tan((double)arg);
    }
    // stage mesh
    {
        const float4* mg = reinterpret_cast<const float4*>(mesh + (size_t)b * L_ * 2);
        float4* msd = reinterpret_cast<float4*>(s_mesh);
        msd[t] = mg[t];
        msd[t + 512] = mg[t + 512];
    }
    __syncthreads();

    // ---- phase 1: per-wave exact rank-409/410 select via value-binned histogram (R6-verified)
    {
        unsigned* hw = reinterpret_cast<unsigned*>(s_u1) + w * 256;          // 1 KB/wave
        float* cw = reinterpret_cast<float*>(s_u1 + 8192) + w * CAPC;        // 1 KB/wave
        for (int rr = 0; rr < 2; ++rr) {
            const int rl = w * 2 + rr;
            const float2 me = s_mesh[n0 + rl];
            *reinterpret_cast<uint4*>(&hw[l * 4]) = make_uint4(0u, 0u, 0u, 0u);
            if (l == 0) s_ccw[w] = 0u;
            LDS_FENCE();
            float myd[32];
            #pragma unroll
            for (int it = 0; it < 32; ++it) {
                const int j = (it << 6) + l;
                const float2 mj = s_mesh[j];
                const float dx = __fsub_rn(me.x, mj.x);
                const float dy = __fsub_rn(me.y, mj.y);
                const float d = __fadd_rn(__fmul_rn(dx, dx), __fmul_rn(dy, dy));
                myd[it] = d;
                int bin = (int)(d * 128.0f); bin = bin < 255 ? bin : 255;
                atomicAdd(&hw[bin], 1u);
            }
            LDS_FENCE();
            const uint4 hv = *reinterpret_cast<const uint4*>(&hw[l * 4]);
            const unsigned p0 = hv.x, p1 = p0 + hv.y, p2 = p1 + hv.z, p3 = p2 + hv.w;
            unsigned sc = p3;
            #pragma unroll
            for (int off = 1; off < 64; off <<= 1) {
                const unsigned uu = __shfl_up(sc, off);
                if (l >= off) sc += uu;
            }
            const unsigned eb = sc - p3;
            const unsigned cum[4] = {eb + p0, eb + p1, eb + p2, eb + p3};
            int flo = -1, fhi = -1; unsigned fbase = 0u;
            #pragma unroll
            for (int e = 0; e < 4; ++e) {
                const unsigned prev = e ? cum[e - 1] : eb;
                if (cum[e] > 409u && prev <= 409u) { flo = l * 4 + e; fbase = prev; }
                if (cum[e] > 410u && prev <= 410u) { fhi = l * 4 + e; }
            }
            const unsigned long long bmlo = __ballot(flo >= 0);
            const int srclo = (int)__builtin_ctzll(bmlo);
            const int lo = __shfl(flo, srclo);
            const unsigned base = __shfl(fbase, srclo);
            const unsigned long long bmhi = __ballot(fhi >= 0);
            const int hi = __shfl(fhi, (int)__builtin_ctzll(bmhi));
            #pragma unroll
            for (int it = 0; it < 32; ++it) {
                const float d = myd[it];
                int bin = (int)(d * 128.0f); bin = bin < 255 ? bin : 255;
                if (bin >= lo && bin <= hi) {
                    const unsigned p = atomicAdd(&s_ccw[w], 1u);
                    if (p < (unsigned)CAPC) cw[p] = d;
                }
            }
            LDS_FENCE();
            const int m = (int)min(s_ccw[w], (unsigned)CAPC);
            const int k409 = 409 - (int)base;
            const int k410 = 410 - (int)base;
            for (int cc0 = 0; cc0 < m; cc0 += 64) {
                const int ci = cc0 + l;
                const float v = (ci < m) ? cw[ci] : 0.0f;
                int lt = 0, le = 0;
                for (int i = 0; i < m; ++i) {
                    const float u = cw[i];
                    lt += (u < v) ? 1 : 0;
                    le += (u <= v) ? 1 : 0;
                }
                if (ci < m) {
                    if (lt <= k409 && k409 < le) s_d409[rl] = v;
                    if (lt <= k410 && k410 < le) s_d410[rl] = v;
                }
            }
            LDS_FENCE();
        }
    }
    __syncthreads();

    // thresholds (exact jnp.quantile lerp, verified R2 path)
    if (t < RB * H_) {
        const int r = t >> 2, h = t & 3;
        const float scl = s_scale[h];
        const float s409 = __fmul_rn(s_d409[r], scl);
        const float s410 = __fmul_rn(s_d410[r], scl);
        const float pos = 0.2f * 2047.0f;
        const float g = pos - 409.0f;
        const float lw = 1.0f - g;
        s_th[r][h] = __fadd_rn(__fmul_rn(s409, lw), __fmul_rn(s410, g));
    }
    __syncthreads();

    // ---- phase 2: K-tiled (KT=64) bf16 A-build + MFMA
    const int rl_b = t >> 5;            // 0..15
    const int h_b  = (t >> 3) & 3;
    const int jg   = t & 7;
    const float2 me_b = s_mesh[n0 + rl_b];
    const float sc_b = s_scale[h_b];
    const float th_b = s_th[rl_b][h_b];
    float wacc = 0.0f;

    const int hw_ = w >> 1;             // head for MFMA
    const int kq  = w & 1;              // k-step within tile
    f32x4 acc[4];
    #pragma unroll
    for (int nq = 0; nq < 4; ++nq) acc[nq] = (f32x4)0.0f;

    const float* inpb = inputs + (size_t)b * L_ * D_;
    char* Abase = s_u1;                 // 4 planes x APS = 8256 B
    char* Bbase = s_u1 + 4 * APS;       // 8192 B

    for (int tile = 0; tile < NTILE; ++tile) {
        __syncthreads();
        // B stage: 1 chunk/thread (8 k x 1 n), global fp32 -> bf16
        unsigned pk0[4];
        {
            const int kb0 = tile * KT + ((t >> 6) << 3);
            const float* pb0 = inpb + (size_t)kb0 * D_ + (t & 63);
            #pragma unroll
            for (int e2 = 0; e2 < 4; ++e2) {
                const float xa = pb0[(2 * e2) * D_];
                const float xb = pb0[(2 * e2 + 1) * D_];
                pk0[e2] = bf16_rne(xa) | (bf16_rne(xb) << 16);
            }
        }
        // A-build: 4 j-pairs per thread for fixed (rl_b, h_b)
        const int k0 = tile * KT;
        #pragma unroll
        for (int m = 0; m < 4; ++m) {
            const int jl = (m << 4) + (jg << 1);
            const float4 mq = *reinterpret_cast<const float4*>(&s_mesh[k0 + jl]);
            const float dx0 = __fsub_rn(me_b.x, mq.x);
            const float dy0 = __fsub_rn(me_b.y, mq.y);
            const float d0 = __fadd_rn(__fmul_rn(dx0, dx0), __fmul_rn(dy0, dy0));
            const float dx1 = __fsub_rn(me_b.x, mq.z);
            const float dy1 = __fsub_rn(me_b.y, mq.w);
            const float d1 = __fadd_rn(__fmul_rn(dx1, dx1), __fmul_rn(dy1, dy1));
            const float x0 = __fmul_rn(d0, sc_b);
            const float x1 = __fmul_rn(d1, sc_b);
            const float e0 = __expf(-x0);
            const float e1 = __expf(-x1);
            const float w0 = (x0 <= th_b) ? e0 : 0.0f;
            const float w1 = (x1 <= th_b) ? e1 : 0.0f;
            wacc += w0 + w1;
            const unsigned u0 = bf16_rne(w0);
            const unsigned u1 = bf16_rne(w1);
            const int ktl = m >> 1;
            const int ql = ((m << 1) + (jg >> 2)) & 3;
            const int chunk = (ktl * 4 + ql) * 16 + rl_b;
            *reinterpret_cast<unsigned*>(Abase + h_b * APS + chunk * 16 + ((jg & 3) << 2)) = u0 | (u1 << 16);
        }
        // commit B to LDS
        *reinterpret_cast<uint4*>(Bbase + t * 16) = make_uint4(pk0[0], pk0[1], pk0[2], pk0[3]);
        __syncthreads();
        // MFMA: wave handles head hw_, k-step kq, all 4 col-quads
        bf16x8 bfr[4];
        #pragma unroll
        for (int nq = 0; nq < 4; ++nq) {
            bfr[nq] = *reinterpret_cast<const bf16x8*>(
                Bbase + ((kq * 4 + (l >> 4)) * 64 + nq * 16 + (l & 15)) * 16);
        }
        const bf16x8 afr = *reinterpret_cast<const bf16x8*>(
            Abase + hw_ * APS + ((kq * 4 + (l >> 4)) * 16 + (l & 15)) * 16);
        #pragma unroll
        for (int nq = 0; nq < 4; ++nq) {
            acc[nq] = __builtin_amdgcn_mfma_f32_16x16x32_bf16(afr, bfr[nq], acc[nq], 0, 0, 0);
        }
    }
    __syncthreads();

    // wsum: reduce over jg lanes, unique writer per (r,h)
    wacc += __shfl_xor(wacc, 1);
    wacc += __shfl_xor(wacc, 2);
    wacc += __shfl_xor(wacc, 4);
    if ((l & 7) == 0) s_wsum[rl_b][h_b] = wacc;
    // zero C region (reuses the shared union region)
    {
        float4* Cz = reinterpret_cast<float4*>(s_u1);
        Cz[t] = make_float4(0.f, 0.f, 0.f, 0.f);
        Cz[t + 512] = make_float4(0.f, 0.f, 0.f, 0.f);
    }
    __syncthreads();
    // reduce k-split accumulator frags into C buffer
    {
        float* Cf = reinterpret_cast<float*>(s_u1);
        #pragma unroll
        for (int nq = 0; nq < 4; ++nq) {
            #pragma unroll
            for (int reg = 0; reg < 4; ++reg) {
                const int row = (l >> 4) * 4 + reg;
                const int col = l & 15;
                atomicAdd(&Cf[((hw_ * 4 + nq) * 16 + row) * 16 + col], acc[nq][reg]);
            }
        }
    }
    __syncthreads();
    // normalize + store conv block
    {
        const float* Cf = reinterpret_cast<const float*>(s_u1);
        const int r = t >> 5;
        const int c0 = (t & 31) << 3;           // 0..248
        const int h = c0 >> 6;
        const int nq = (c0 >> 4) & 3;
        const int cl = c0 & 15;                 // 0 or 8
        const float wsv = s_wsum[r][h];
        const float inv = (wsv != 0.0f) ? 1.0f / wsv : 0.0f;
        const float* src = &Cf[((h * 4 + nq) * 16 + r) * 16 + cl];
        float4 r0 = *reinterpret_cast<const float4*>(src);
        float4 r1 = *reinterpret_cast<const float4*>(src + 4);
        r0.x *= inv; r0.y *= inv; r0.z *= inv; r0.w *= inv;
        r1.x *= inv; r1.y *= inv; r1.z *= inv; r1.w *= inv;
        float* op = out + (size_t)(b * L_ + n0 + r) * OUTW + D_ + c0;
        *reinterpret_cast<float4*>(op) = r0;
        *reinterpret_cast<float4*>(op + 4) = r1;
    }
    // exact fp32 passthrough of inputs into out[:, :, 0:64]
    {
        const int r = t >> 5;
        const int c0 = (t & 31) << 1;
        const float2 v = *reinterpret_cast<const float2*>(
            inputs + ((size_t)b * L_ + n0 + r) * D_ + c0);
        *reinterpret_cast<float2*>(out + (size_t)(b * L_ + n0 + r) * OUTW + c0) = v;
    }
}

extern "C" void kernel_launch(void* const* d_in, const int* in_sizes, int n_in,
                              void* d_out, int out_size, void* d_ws, size_t ws_size,
                              hipStream_t stream) {
    const float* mesh   = (const float*)d_in[0];
    const float* inputs = (const float*)d_in[1];
    const float* lmda   = (const float*)d_in[2];
    float* out = (float*)d_out;
    (void)in_sizes; (void)n_in; (void)out_size; (void)d_ws; (void)ws_size;
    hipLaunchKernelGGL(posatt_kernel, dim3(B_ * (L_ / RB)), dim3(512), 0, stream,
                       mesh, inputs, lmda, out);
}

// Round 8
// 145.068 us; speedup vs baseline: 1.1035x; 1.1035x over previous
//
#include <hip/hip_runtime.h>
#include <math.h>

#ifndef M_PI
#define M_PI 3.14159265358979323846
#endif

namespace {
constexpr int B_ = 4;
constexpr int L_ = 2048;
constexpr int D_ = 64;
constexpr int H_ = 4;
constexpr int RB = 16;          // rows per block
constexpr int KT = 64;          // K-tile
constexpr int NTILE = L_ / KT;  // 32
constexpr int CAPC = 256;       // per-wave candidate capacity
constexpr int OUTW = D_ + H_ * D_;  // 320
constexpr int APS = 2064;       // A plane stride bytes (64*16*2 + 16 pad)
}

typedef __attribute__((ext_vector_type(8))) short bf16x8;
typedef __attribute__((ext_vector_type(4))) float f32x4;

__device__ __forceinline__ unsigned bf16_rne(float x) {
    unsigned u = __float_as_uint(x);
    return (u + 0x7fffu + ((u >> 16) & 1u)) >> 16;
}

// wait lgkmcnt(0) only (vmcnt=63, expcnt=7): gfx9 imm = (vm_hi<<14)|(lgkm<<8)|(exp<<4)|vm_lo
#define LDS_FENCE() __builtin_amdgcn_s_waitcnt(0xC07F)

__global__ __launch_bounds__(512, 8) void posatt_kernel(
    const float* __restrict__ mesh,     // (B,L,2)
    const float* __restrict__ inputs,   // (B,L,D)
    const float* __restrict__ lmda,     // (H)
    float* __restrict__ out)            // (B,L,320)
{
    __shared__ __align__(16) float2 s_mesh[L_];       // 16 KB
    // time-shared region: phase1 hist(8K)+cand(8K) | phase2 A(8256)+B(8192) | epilogue C(16K)
    __shared__ __align__(16) char s_u1[16448];
    __shared__ float s_scale[H_];
    __shared__ float s_th[RB][H_];
    __shared__ float s_d409[RB], s_d410[RB];
    __shared__ float s_wsum[RB][H_];
    __shared__ unsigned s_ccw[8];

    const int t = threadIdx.x;
    const int l = t & 63;
    const int w = t >> 6;               // 8 waves
    const int blk = blockIdx.x;         // 512
    const int b = blk >> 7;
    const int n0 = (blk & 127) * RB;

    // per-head scale (exact, verified R2 path)
    if (t < H_) {
        const double lam = (double)lmda[t];
        const float C = (float)(0.25 * M_PI * (1.0 - 1e-07));
        const float s1 = (float)sin(lam);
        const float arg = __fmul_rn(C, __fadd_rn(1.0f, s1));
        s_scale[t] = (float)tan((double)arg);
    }
    // stage mesh
    {
        const float4* mg = reinterpret_cast<const float4*>(mesh + (size_t)b * L_ * 2);
        float4* msd = reinterpret_cast<float4*>(s_mesh);
        msd[t] = mg[t];
        msd[t + 512] = mg[t + 512];
    }
    __syncthreads();

    // ---- phase 1: per-wave exact rank-409/410 select via value-binned histogram
    // (R6-verified math; distances RECOMPUTED per pass — no myd[] register cache, no spills)
    {
        unsigned* hw = reinterpret_cast<unsigned*>(s_u1) + w * 256;          // 1 KB/wave
        float* cw = reinterpret_cast<float*>(s_u1 + 8192) + w * CAPC;        // 1 KB/wave
        for (int rr = 0; rr < 2; ++rr) {
            const int rl = w * 2 + rr;
            const float2 me = s_mesh[n0 + rl];
            *reinterpret_cast<uint4*>(&hw[l * 4]) = make_uint4(0u, 0u, 0u, 0u);
            if (l == 0) s_ccw[w] = 0u;
            LDS_FENCE();
            #pragma unroll 1
            for (int it = 0; it < 32; ++it) {
                const int j = (it << 6) + l;
                const float2 mj = s_mesh[j];
                const float dx = __fsub_rn(me.x, mj.x);
                const float dy = __fsub_rn(me.y, mj.y);
                const float d = __fadd_rn(__fmul_rn(dx, dx), __fmul_rn(dy, dy));
                int bin = (int)(d * 128.0f); bin = bin < 255 ? bin : 255;
                atomicAdd(&hw[bin], 1u);
            }
            LDS_FENCE();
            const uint4 hv = *reinterpret_cast<const uint4*>(&hw[l * 4]);
            const unsigned p0 = hv.x, p1 = p0 + hv.y, p2 = p1 + hv.z, p3 = p2 + hv.w;
            unsigned sc = p3;
            #pragma unroll
            for (int off = 1; off < 64; off <<= 1) {
                const unsigned uu = __shfl_up(sc, off);
                if (l >= off) sc += uu;
            }
            const unsigned eb = sc - p3;
            const unsigned cum[4] = {eb + p0, eb + p1, eb + p2, eb + p3};
            int flo = -1, fhi = -1; unsigned fbase = 0u;
            #pragma unroll
            for (int e = 0; e < 4; ++e) {
                const unsigned prev = e ? cum[e - 1] : eb;
                if (cum[e] > 409u && prev <= 409u) { flo = l * 4 + e; fbase = prev; }
                if (cum[e] > 410u && prev <= 410u) { fhi = l * 4 + e; }
            }
            const unsigned long long bmlo = __ballot(flo >= 0);
            const int srclo = (int)__builtin_ctzll(bmlo);
            const int lo = __shfl(flo, srclo);
            const unsigned base = __shfl(fbase, srclo);
            const unsigned long long bmhi = __ballot(fhi >= 0);
            const int hi = __shfl(fhi, (int)__builtin_ctzll(bmhi));
            #pragma unroll 1
            for (int it = 0; it < 32; ++it) {
                const int j = (it << 6) + l;
                const float2 mj = s_mesh[j];
                const float dx = __fsub_rn(me.x, mj.x);
                const float dy = __fsub_rn(me.y, mj.y);
                const float d = __fadd_rn(__fmul_rn(dx, dx), __fmul_rn(dy, dy));
                int bin = (int)(d * 128.0f); bin = bin < 255 ? bin : 255;
                if (bin >= lo && bin <= hi) {
                    const unsigned p = atomicAdd(&s_ccw[w], 1u);
                    if (p < (unsigned)CAPC) cw[p] = d;
                }
            }
            LDS_FENCE();
            const int m = (int)min(s_ccw[w], (unsigned)CAPC);
            const int k409 = 409 - (int)base;
            const int k410 = 410 - (int)base;
            #pragma unroll 1
            for (int cc0 = 0; cc0 < m; cc0 += 64) {
                const int ci = cc0 + l;
                const float v = (ci < m) ? cw[ci] : 0.0f;
                int lt = 0, le = 0;
                #pragma unroll 1
                for (int i = 0; i < m; ++i) {
                    const float u = cw[i];
                    lt += (u < v) ? 1 : 0;
                    le += (u <= v) ? 1 : 0;
                }
                if (ci < m) {
                    if (lt <= k409 && k409 < le) s_d409[rl] = v;
                    if (lt <= k410 && k410 < le) s_d410[rl] = v;
                }
            }
            LDS_FENCE();
        }
    }
    __syncthreads();

    // thresholds (exact jnp.quantile lerp, verified R2 path)
    if (t < RB * H_) {
        const int r = t >> 2, h = t & 3;
        const float scl = s_scale[h];
        const float s409 = __fmul_rn(s_d409[r], scl);
        const float s410 = __fmul_rn(s_d410[r], scl);
        const float pos = 0.2f * 2047.0f;
        const float g = pos - 409.0f;
        const float lw = 1.0f - g;
        s_th[r][h] = __fadd_rn(__fmul_rn(s409, lw), __fmul_rn(s410, g));
    }
    __syncthreads();

    // ---- phase 2: K-tiled (KT=64) bf16 A-build + MFMA
    const int rl_b = t >> 5;            // 0..15
    const int h_b  = (t >> 3) & 3;
    const int jg   = t & 7;
    const float2 me_b = s_mesh[n0 + rl_b];
    const float sc_b = s_scale[h_b];
    const float th_b = s_th[rl_b][h_b];
    float wacc = 0.0f;

    const int hw_ = w >> 1;             // head for MFMA
    const int kq  = w & 1;              // k-step within tile
    f32x4 acc[4];
    #pragma unroll
    for (int nq = 0; nq < 4; ++nq) acc[nq] = (f32x4)0.0f;

    const float* inpb = inputs + (size_t)b * L_ * D_;
    char* Abase = s_u1;                 // 4 planes x APS = 8256 B
    char* Bbase = s_u1 + 4 * APS;       // 8192 B

    #pragma unroll 1
    for (int tile = 0; tile < NTILE; ++tile) {
        __syncthreads();
        // B stage: 1 chunk/thread (8 k x 1 n), global fp32 -> bf16
        unsigned pk0[4];
        {
            const int kb0 = tile * KT + ((t >> 6) << 3);
            const float* pb0 = inpb + (size_t)kb0 * D_ + (t & 63);
            #pragma unroll
            for (int e2 = 0; e2 < 4; ++e2) {
                const float xa = pb0[(2 * e2) * D_];
                const float xb = pb0[(2 * e2 + 1) * D_];
                pk0[e2] = bf16_rne(xa) | (bf16_rne(xb) << 16);
            }
        }
        // A-build: 4 j-pairs per thread for fixed (rl_b, h_b)
        const int k0 = tile * KT;
        #pragma unroll
        for (int m = 0; m < 4; ++m) {
            const int jl = (m << 4) + (jg << 1);
            const float4 mq = *reinterpret_cast<const float4*>(&s_mesh[k0 + jl]);
            const float dx0 = __fsub_rn(me_b.x, mq.x);
            const float dy0 = __fsub_rn(me_b.y, mq.y);
            const float d0 = __fadd_rn(__fmul_rn(dx0, dx0), __fmul_rn(dy0, dy0));
            const float dx1 = __fsub_rn(me_b.x, mq.z);
            const float dy1 = __fsub_rn(me_b.y, mq.w);
            const float d1 = __fadd_rn(__fmul_rn(dx1, dx1), __fmul_rn(dy1, dy1));
            const float x0 = __fmul_rn(d0, sc_b);
            const float x1 = __fmul_rn(d1, sc_b);
            const float e0 = __expf(-x0);
            const float e1 = __expf(-x1);
            const float w0 = (x0 <= th_b) ? e0 : 0.0f;
            const float w1 = (x1 <= th_b) ? e1 : 0.0f;
            wacc += w0 + w1;
            const unsigned u0 = bf16_rne(w0);
            const unsigned u1 = bf16_rne(w1);
            const int ktl = m >> 1;
            const int ql = ((m << 1) + (jg >> 2)) & 3;
            const int chunk = (ktl * 4 + ql) * 16 + rl_b;
            *reinterpret_cast<unsigned*>(Abase + h_b * APS + chunk * 16 + ((jg & 3) << 2)) = u0 | (u1 << 16);
        }
        // commit B to LDS
        *reinterpret_cast<uint4*>(Bbase + t * 16) = make_uint4(pk0[0], pk0[1], pk0[2], pk0[3]);
        __syncthreads();
        // MFMA: wave handles head hw_, k-step kq, all 4 col-quads
        bf16x8 bfr[4];
        #pragma unroll
        for (int nq = 0; nq < 4; ++nq) {
            bfr[nq] = *reinterpret_cast<const bf16x8*>(
                Bbase + ((kq * 4 + (l >> 4)) * 64 + nq * 16 + (l & 15)) * 16);
        }
        const bf16x8 afr = *reinterpret_cast<const bf16x8*>(
            Abase + hw_ * APS + ((kq * 4 + (l >> 4)) * 16 + (l & 15)) * 16);
        #pragma unroll
        for (int nq = 0; nq < 4; ++nq) {
            acc[nq] = __builtin_amdgcn_mfma_f32_16x16x32_bf16(afr, bfr[nq], acc[nq], 0, 0, 0);
        }
    }
    __syncthreads();

    // wsum: reduce over jg lanes, unique writer per (r,h)
    wacc += __shfl_xor(wacc, 1);
    wacc += __shfl_xor(wacc, 2);
    wacc += __shfl_xor(wacc, 4);
    if ((l & 7) == 0) s_wsum[rl_b][h_b] = wacc;
    // zero C region (reuses the shared union region)
    {
        float4* Cz = reinterpret_cast<float4*>(s_u1);
        Cz[t] = make_float4(0.f, 0.f, 0.f, 0.f);
        Cz[t + 512] = make_float4(0.f, 0.f, 0.f, 0.f);
    }
    __syncthreads();
    // reduce k-split accumulator frags into C buffer
    {
        float* Cf = reinterpret_cast<float*>(s_u1);
        #pragma unroll
        for (int nq = 0; nq < 4; ++nq) {
            #pragma unroll
            for (int reg = 0; reg < 4; ++reg) {
                const int row = (l >> 4) * 4 + reg;
                const int col = l & 15;
                atomicAdd(&Cf[((hw_ * 4 + nq) * 16 + row) * 16 + col], acc[nq][reg]);
            }
        }
    }
    __syncthreads();
    // normalize + store conv block
    {
        const float* Cf = reinterpret_cast<const float*>(s_u1);
        const int r = t >> 5;
        const int c0 = (t & 31) << 3;           // 0..248
        const int h = c0 >> 6;
        const int nq = (c0 >> 4) & 3;
        const int cl = c0 & 15;                 // 0 or 8
        const float wsv = s_wsum[r][h];
        const float inv = (wsv != 0.0f) ? 1.0f / wsv : 0.0f;
        const float* src = &Cf[((h * 4 + nq) * 16 + r) * 16 + cl];
        float4 r0 = *reinterpret_cast<const float4*>(src);
        float4 r1 = *reinterpret_cast<const float4*>(src + 4);
        r0.x *= inv; r0.y *= inv; r0.z *= inv; r0.w *= inv;
        r1.x *= inv; r1.y *= inv; r1.z *= inv; r1.w *= inv;
        float* op = out + (size_t)(b * L_ + n0 + r) * OUTW + D_ + c0;
        *reinterpret_cast<float4*>(op) = r0;
        *reinterpret_cast<float4*>(op + 4) = r1;
    }
    // exact fp32 passthrough of inputs into out[:, :, 0:64]
    {
        const int r = t >> 5;
        const int c0 = (t & 31) << 1;
        const float2 v = *reinterpret_cast<const float2*>(
            inputs + ((size_t)b * L_ + n0 + r) * D_ + c0);
        *reinterpret_cast<float2*>(out + (size_t)(b * L_ + n0 + r) * OUTW + c0) = v;
    }
}

extern "C" void kernel_launch(void* const* d_in, const int* in_sizes, int n_in,
                              void* d_out, int out_size, void* d_ws, size_t ws_size,
                              hipStream_t stream) {
    const float* mesh   = (const float*)d_in[0];
    const float* inputs = (const float*)d_in[1];
    const float* lmda   = (const float*)d_in[2];
    float* out = (float*)d_out;
    (void)in_sizes; (void)n_in; (void)out_size; (void)d_ws; (void)ws_size;
    hipLaunchKernelGGL(posatt_kernel, dim3(B_ * (L_ / RB)), dim3(512), 0, stream,
                       mesh, inputs, lmda, out);
}